// Round 8
// baseline (140.775 us; speedup 1.0000x reference)
//
#include <hip/hip_runtime.h>
#include <stdint.h>

#define SS 2048
#define BB 16
#define DD 128
#define DVV 128
#define BQ 32
#define BK 32
#define NTILES (SS / BK)        // 64 k-tiles per batch
#define TILE_HW 4096            // 8 KB tile image = 4096 halfwords

typedef __attribute__((ext_vector_type(8))) short short8;
typedef __attribute__((ext_vector_type(4))) float float4v;

typedef __attribute__((address_space(1))) const void glob_cv;
typedef __attribute__((address_space(3))) void lds_v;

// RTNE float -> bf16 (inputs finite)
__device__ __forceinline__ short f2bf(float f) {
  union { float f; uint32_t u; } x;
  x.f = f;
  uint32_t r = x.u + 0x7fffu + ((x.u >> 16) & 1u);
  return (short)(r >> 16);
}
__device__ __forceinline__ float bf2f(short h) {
  union { uint32_t u; float f; } y;
  y.u = ((uint32_t)(uint16_t)h) << 16;
  return y.f;
}

// key permutation kappa: PV fragment slot (quad, j) <-> key  (verified R4-R7)
__device__ __forceinline__ int kappa(int quad, int j) {
  return (j < 4) ? (quad * 4 + j) : (16 + quad * 4 + (j - 4));
}

// ---- preconvert K and V (VERBATIM R5/R7, verified) ----
__global__ __launch_bounds__(256) void conv_kv(
    const float* __restrict__ kg, const float* __restrict__ vg,
    short* __restrict__ kimg, short* __restrict__ vimg) {
  __shared__ short tile[BK][136];
  const int t = blockIdx.x, b = blockIdx.y;
  if (blockIdx.z == 0) {
    short* out = kimg + ((size_t)(b * NTILES + t)) * TILE_HW;
#pragma unroll
    for (int p = 0; p < 2; ++p) {
      const int ch = threadIdx.x + p * 256;  // key*16 + c
      const int key = ch >> 4, c = ch & 15;
      const float* src = kg + ((size_t)(t * BK + key) * BB + b) * DD + c * 8;
      float4v f0 = *(const float4v*)src;
      float4v f1 = *(const float4v*)(src + 4);
      short8 s;
#pragma unroll
      for (int i = 0; i < 4; ++i) { s[i] = f2bf(f0[i]); s[4 + i] = f2bf(f1[i]); }
      *(short8*)(out + key * 128 + ((c ^ (key & 7)) * 8)) = s;
    }
  } else {
    short* out = vimg + ((size_t)(b * NTILES + t)) * TILE_HW;
#pragma unroll
    for (int p = 0; p < 2; ++p) {
      const int ch = threadIdx.x + p * 256;
      const int key = ch >> 4, fc = ch & 15;
      const float* src = vg + ((size_t)(t * BK + key) * BB + b) * DVV + fc * 8;
      float4v f0 = *(const float4v*)src;
      float4v f1 = *(const float4v*)(src + 4);
      short8 s;
#pragma unroll
      for (int i = 0; i < 4; ++i) { s[i] = f2bf(f0[i]); s[4 + i] = f2bf(f1[i]); }
      *(short8*)&tile[key][fc * 8] = s;
    }
    __syncthreads();
#pragma unroll
    for (int p = 0; p < 2; ++p) {
      const int idx = threadIdx.x + p * 256;        // chunk index in read order
      const int nt = idx >> 6, quad = (idx >> 4) & 3, mm = idx & 15;
      const int dv = nt * 16 + mm;
      short8 s;
#pragma unroll
      for (int j = 0; j < 8; ++j) s[j] = tile[kappa(quad, j)][dv];
      *(short8*)(out + idx * 8) = s;
    }
  }
}

// ---- attention: 4 wave-private pipelines (tile stride 4), 32 q-rows/wave,
//      no barriers in the loop (single-owner buffers + own-vmcnt discipline) ----
__global__ __launch_bounds__(256) void attn_fwd(
    const float* __restrict__ qg, const short* __restrict__ kimg,
    const short* __restrict__ vimg, float* __restrict__ og) {
  __shared__ __align__(16) short smem[8 * TILE_HW];  // 64 KB: K[4] | V[4]

  const int tid  = threadIdx.x;
  const int tpar = tid >> 6;    // wave's tile parity (stride-4 tile set)
  const int lane = tid & 63;
  const int m    = lane & 15;
  const int quad = lane >> 4;
  const int bid  = blockIdx.x;
  const int qt   = (NTILES - 1) - (bid >> 4);  // LPT: longest blocks first
  const int b    = bid & 15;
  const int q0   = qt * BQ;
  const int qrowA = q0 + m;         // q-half A rows q0..q0+15
  const int qrowB = q0 + 16 + m;    // q-half B rows q0+16..q0+31

  // Q fragments (B operand), 1/sqrt(D)*log2(e) folded (verbatim R5/R7 x2)
  const float cscale = 0.08838834764831845f * 1.4426950408889634f;
  short8 qfragA[4], qfragB[4];
#pragma unroll
  for (int ks = 0; ks < 4; ++ks) {
    const float* qpA = qg + ((size_t)qrowA * BB + b) * DD + ks * 32 + quad * 8;
    const float* qpB = qg + ((size_t)qrowB * BB + b) * DD + ks * 32 + quad * 8;
    float4v a0 = *(const float4v*)qpA, a1 = *(const float4v*)(qpA + 4);
    float4v b0 = *(const float4v*)qpB, b1 = *(const float4v*)(qpB + 4);
    short8 fa, fb;
#pragma unroll
    for (int i = 0; i < 4; ++i) {
      fa[i] = f2bf(a0[i] * cscale); fa[4 + i] = f2bf(a1[i] * cscale);
      fb[i] = f2bf(b0[i] * cscale); fb[4 + i] = f2bf(b1[i] * cscale);
    }
    qfragA[ks] = fa; qfragB[ks] = fb;
  }

  float4v oaccA[8], oaccB[8];
#pragma unroll
  for (int i = 0; i < 8; ++i) {
    oaccA[i] = (float4v){0.f, 0.f, 0.f, 0.f};
    oaccB[i] = (float4v){0.f, 0.f, 0.f, 0.f};
  }
  float psumA = 0.f, psumB = 0.f;

  // wave-private buffers: only wave tpar writes AND reads these
  short* const kb = smem + tpar * TILE_HW;
  short* const vb = smem + (4 + tpar) * TILE_HW;
  const short* ksrc = kimg + (size_t)b * NTILES * TILE_HW + lane * 8;
  const short* vsrc = vimg + (size_t)b * NTILES * TILE_HW + lane * 8;

  const int ntile = qt + 1;
  for (int t = tpar; t < ntile; t += 4) {
    // prior round's DMA + LDS reads fully drained (own counters only)
    __builtin_amdgcn_s_waitcnt(0x0000);
    {
      const short* sk = ksrc + (size_t)t * TILE_HW;
      const short* sv2 = vsrc + (size_t)t * TILE_HW;
#pragma unroll
      for (int j = 0; j < 8; ++j) {
        __builtin_amdgcn_global_load_lds((glob_cv*)(sk + j * 512),
                                         (lds_v*)(kb + j * 512), 16, 0, 0);
        __builtin_amdgcn_global_load_lds((glob_cv*)(sv2 + j * 512),
                                         (lds_v*)(vb + j * 512), 16, 0, 0);
      }
    }
    __builtin_amdgcn_s_waitcnt(0x0F70);  // vmcnt(0): tiles landed in LDS

    // ---- S = K·Q^T for both q-halves (kf loaded once) ----
    float4v sA0 = {0.f,0.f,0.f,0.f}, sA1 = {0.f,0.f,0.f,0.f};
    float4v sB0 = {0.f,0.f,0.f,0.f}, sB1 = {0.f,0.f,0.f,0.f};
#pragma unroll
    for (int ks = 0; ks < 4; ++ks) {
      const int c = ks * 4 + quad;
      short8 kf0 = *(const short8*)&kb[m * 128 + ((c ^ (m & 7)) * 8)];
      short8 kf1 = *(const short8*)&kb[(16 + m) * 128 + ((c ^ (m & 7)) * 8)];
      sA0 = __builtin_amdgcn_mfma_f32_16x16x32_bf16(kf0, qfragA[ks], sA0, 0, 0, 0);
      sA1 = __builtin_amdgcn_mfma_f32_16x16x32_bf16(kf1, qfragA[ks], sA1, 0, 0, 0);
      sB0 = __builtin_amdgcn_mfma_f32_16x16x32_bf16(kf0, qfragB[ks], sB0, 0, 0, 0);
      sB1 = __builtin_amdgcn_mfma_f32_16x16x32_bf16(kf1, qfragB[ks], sB1, 0, 0, 0);
    }
    float svA[8], svB[8];
#pragma unroll
    for (int r = 0; r < 4; ++r) {
      svA[r] = sA0[r]; svA[4 + r] = sA1[r];
      svB[r] = sB0[r]; svB[4 + r] = sB1[r];
    }

    const int kt0 = t * BK;
    if (kt0 + BK - 1 > q0) {       // diagonal tile for half A (wave-uniform)
#pragma unroll
      for (int j = 0; j < 8; ++j)
        if (kt0 + kappa(quad, j) > qrowA) svA[j] = -1e30f;
    }
    if (kt0 + BK - 1 > q0 + 16) {  // diagonal tile for half B
#pragma unroll
      for (int j = 0; j < 8; ++j)
        if (kt0 + kappa(quad, j) > qrowB) svB[j] = -1e30f;
    }

    // ---- fixed-reference softmax (verbatim R5/R7, x2) ----
    short8 pfragA, pfragB;
#pragma unroll
    for (int j = 0; j < 8; ++j) {
      float pA = exp2f(svA[j]);
      float pB = exp2f(svB[j]);
      short hA = f2bf(pA), hB = f2bf(pB);
      pfragA[j] = hA; pfragB[j] = hB;
      psumA += bf2f(hA); psumB += bf2f(hB);
    }

    // ---- PV for both q-halves (vf loaded once) ----
#pragma unroll
    for (int nt = 0; nt < 8; ++nt) {
      short8 vf = *(const short8*)&vb[nt * 512 + lane * 8];
      oaccA[nt] = __builtin_amdgcn_mfma_f32_16x16x32_bf16(pfragA, vf, oaccA[nt], 0, 0, 0);
      oaccB[nt] = __builtin_amdgcn_mfma_f32_16x16x32_bf16(pfragB, vf, oaccB[nt], 0, 0, 0);
    }
  }

  // ---- combine: waves 1..3 -> wave 0 (partials are exactly additive) ----
  __syncthreads();  // all loop work done (each wave drained itself)
  float* const cw = (float*)smem;  // overlay scratch: 3*64*67*4 = 51,456 B
  if (tpar != 0) {
    float* p = cw + (size_t)((tpar - 1) * 64 + lane) * 67;
#pragma unroll
    for (int nt = 0; nt < 8; ++nt) {
      *(float4v*)(p + nt * 4)      = oaccA[nt];
      *(float4v*)(p + 32 + nt * 4) = oaccB[nt];
    }
    p[64] = psumA;
    p[65] = psumB;
  }
  __syncthreads();
  if (tpar == 0) {
#pragma unroll
    for (int w = 0; w < 3; ++w) {
      const float* p = cw + (size_t)(w * 64 + lane) * 67;
#pragma unroll
      for (int nt = 0; nt < 8; ++nt) {
        oaccA[nt] += *(const float4v*)(p + nt * 4);
        oaccB[nt] += *(const float4v*)(p + 32 + nt * 4);
      }
      psumA += p[64];
      psumB += p[65];
    }

    // ---- epilogue (verbatim R5/R7, x2) ----
    float lA = psumA, lB = psumB;
    lA += __shfl_xor(lA, 16, 64); lA += __shfl_xor(lA, 32, 64);
    lB += __shfl_xor(lB, 16, 64); lB += __shfl_xor(lB, 32, 64);
    const float liA = 1.0f / lA, liB = 1.0f / lB;
    float l4A[4], l4B[4];
#pragma unroll
    for (int rr = 0; rr < 4; ++rr) {
      l4A[rr] = __shfl(liA, quad * 4 + rr, 64);
      l4B[rr] = __shfl(liB, quad * 4 + rr, 64);
    }
#pragma unroll
    for (int rr = 0; rr < 4; ++rr) {
      const int gA = q0 + quad * 4 + rr;
      const int gB = q0 + 16 + quad * 4 + rr;
      float* opA = og + ((size_t)gA * BB + b) * DVV + m;
      float* opB = og + ((size_t)gB * BB + b) * DVV + m;
#pragma unroll
      for (int nt = 0; nt < 8; ++nt) {
        opA[nt * 16] = oaccA[nt][rr] * l4A[rr];
        opB[nt * 16] = oaccB[nt][rr] * l4B[rr];
      }
    }
  }
}

extern "C" void kernel_launch(void* const* d_in, const int* in_sizes, int n_in,
                              void* d_out, int out_size, void* d_ws, size_t ws_size,
                              hipStream_t stream) {
  const float* q = (const float*)d_in[0];
  const float* k = (const float*)d_in[1];
  const float* v = (const float*)d_in[2];
  float* out = (float*)d_out;
  short* kimg = (short*)d_ws;
  short* vimg = kimg + (size_t)BB * NTILES * TILE_HW;  // 8.39 MB each

  conv_kv<<<dim3(NTILES, BB, 2), 256, 0, stream>>>(k, v, kimg, vimg);
  attn_fwd<<<dim3(SS / BQ * BB), 256, 0, stream>>>(q, kimg, vimg, out);
}